// Round 11
// baseline (906.911 us; speedup 1.0000x reference)
//
#include <hip/hip_runtime.h>

typedef unsigned short u16;
typedef unsigned int   u32;

typedef __attribute__((ext_vector_type(8))) short short8;   // 8 bf16 (4 VGPRs)
typedef __attribute__((ext_vector_type(4))) float f32x4;    // MFMA acc

union Frag { u32 u[4]; short8 s; };

__device__ __forceinline__ u32 fbits(float f){ union{float f;u32 u;}x; x.f=f; return x.u; }
__device__ __forceinline__ float bitsf(u32 u){ union{u32 u;float f;}x; x.u=u; return x.f; }
__device__ __forceinline__ u32 pack_trunc(float a, float b){
    return __builtin_amdgcn_perm(fbits(b), fbits(a), 0x07060302u);
}
__device__ __forceinline__ u32 bf16_rne(float a){
    u32 u = fbits(a); return (u + 0x7FFFu + ((u >> 16) & 1u)) >> 16;
}
__device__ __forceinline__ u32 pack_rne(float a, float b){
    return bf16_rne(a) | (bf16_rne(b) << 16);
}
__device__ __forceinline__ float sigmoidf_(float x){
    return __builtin_amdgcn_rcpf(1.0f + __expf(-x));
}
__device__ __forceinline__ float tanhf_(float x){
    return 1.0f - 2.0f * __builtin_amdgcn_rcpf(__expf(2.0f * x) + 1.0f);
}

// LDS: 40,192 B -> 4 blocks/CU (grid-pinned anyway: 1024 blocks / 256 CU).
// part: ping-pong [buf][dest-wave][ti*16+sq][20]; stride 20 dw -> bank-quad
// 4*((5sq+q)%8): permutation over 8 consecutive lanes -> conflict-free b128.
struct __align__(16) SharedMem {
    union {
        float part[2][2][6 * 16 * 20];   // 30720 B — loop only
        struct {                         // 9476 B — tail weights
            float wl[1152];
            float bl[16];
            float wcf[640];
            float bcf[20];
            float wcc[80];
            float bcc[20];
            float wcm[400];
            float bcm[20];
            float wfin[20];
            float bfin;
        } tw;
    };
    float h[16 * 68];      // 4352 B — hidden state [sq][k]
    float wih[768];        // 3072 B
    union {
        struct { float u[2][64]; float gnh[64]; } lp;   // loop: 768 B
        struct { float line[2][128]; float pp[2][128]; } tl;  // tail: 2048 B
    };
};

__global__ __launch_bounds__(128, 2)
void FRAPRQ_fused_kernel(
    const float* __restrict__ feat,       // (B,16)
    const float* __restrict__ hist,       // (B,64,24)
    const int*   __restrict__ relation,   // (8,7)
    const float* __restrict__ emb_phase,  // (2,4)
    const float* __restrict__ Wv,         // (4,1)
    const float* __restrict__ bv,         // (4)
    const float* __restrict__ Wh,         // (4,3)
    const float* __restrict__ bh,         // (4)
    const float* __restrict__ Wih,        // (192,4)
    const float* __restrict__ Whh,        // (192,64)
    const float* __restrict__ bih,        // (192)
    const float* __restrict__ bhh,        // (192)
    const float* __restrict__ Wl,         // (16,72)
    const float* __restrict__ bl,         // (16)
    const float* __restrict__ emb_const,  // (2,4)
    const float* __restrict__ Wcf,        // (20,32)
    const float* __restrict__ bcf,        // (20)
    const float* __restrict__ Wcc,        // (20,4)
    const float* __restrict__ bcc,        // (20)
    const float* __restrict__ Wcm,        // (20,20)
    const float* __restrict__ bcm,        // (20)
    const float* __restrict__ Wfin,      // (1,20)
    const float* __restrict__ bfin,      // (1)
    float* __restrict__ out)             // (B,8)
{
    __shared__ SharedMem sm;
    const int tid  = threadIdx.x;        // 0..127
    const int g    = tid >> 6;           // K-half: 0 -> k 0..31, 1 -> k 32..63
    const int lane = tid & 63;
    const int sq   = lane & 15;          // MFMA column: local seq (2 b's x 8 lanes)
    const int q    = lane >> 4;          // MFMA quad
    const int b_base = blockIdx.x * 2;

    // ---- cooperative staging ----
    for (int i = tid; i < 768; i += 128) sm.wih[i] = Wih[i];
    if (tid < 64) sm.lp.gnh[tid] = bhh[128 + tid];
    for (int i = tid; i < 16 * 68; i += 128) sm.h[i] = 0.0f;

    // ---- A-fragments for this wave's K-half (hi + lo, in registers) ----
    Frag ahi[12], alo[12];
    #pragma unroll
    for (int mt = 0; mt < 12; ++mt){
        const float* wp = Whh + (16 * mt + sq) * 64 + 32 * g + 8 * q;
        float f[8];
        #pragma unroll
        for (int i = 0; i < 8; ++i) f[i] = wp[i];
        #pragma unroll
        for (int p = 0; p < 4; ++p){
            const u32 hi = pack_rne(f[2*p], f[2*p+1]);
            ahi[mt].u[p] = hi;
            const float l0 = f[2*p]   - bitsf((hi & 0xFFFFu) << 16);
            const float l1 = f[2*p+1] - bitsf(hi & 0xFFFF0000u);
            alo[mt].u[p] = pack_rne(l0, l1);
        }
    }

    // ---- per-lane biases for OWNED rows j = 32g + 16mp + 4q + r ----
    float bR[2][4], bZ[2][4], bNi[2][4];
    #pragma unroll
    for (int mp = 0; mp < 2; ++mp){
        #pragma unroll
        for (int r = 0; r < 4; ++r){
            const int j = 32 * g + 16 * mp + 4 * q + r;
            bR[mp][r]  = bih[j]       + bhh[j];
            bZ[mp][r]  = bih[64 + j]  + bhh[64 + j];
            bNi[mp][r] = bih[128 + j];
        }
    }

    // ---- u path: lane computes u[s=sq][c=q]; redundant per wave ----
    const int bs = b_base + (sq >> 3);
    const int ls = sq & 7;
    const float* hb = hist + (size_t)bs * 1536;
    const float wh0 = Wh[q*3+0], wh1 = Wh[q*3+1], wh2 = Wh[q*3+2], bhc = bh[q];
    float* uw = &sm.lp.u[g][0];
    {
        const float y0 = hb[ls], y1 = hb[ls + 8], y2 = hb[ls + 16];
        uw[sq * 4 + q] = sigmoidf_(fmaf(wh0, y0, fmaf(wh1, y1, fmaf(wh2, y2, bhc))));
    }
    float x0 = hb[24 + ls], x1 = hb[24 + ls + 8], x2 = hb[24 + ls + 16];

    float hreg[2][4];
    #pragma unroll
    for (int mp = 0; mp < 2; ++mp)
        #pragma unroll
        for (int r = 0; r < 4; ++r) hreg[mp][r] = 0.0f;

    __syncthreads();   // staging + h init visible

    #pragma unroll 1
    for (int t = 0; t < 64; ++t){
        // B fragment from h(t-1), own K-half (rows this wave wrote itself)
        Frag bhi, blo;
        {
            const float4 hA = *(const float4*)&sm.h[sq*68 + 32*g + 8*q];
            const float4 hB = *(const float4*)&sm.h[sq*68 + 32*g + 8*q + 4];
            const float f[8] = {hA.x, hA.y, hA.z, hA.w, hB.x, hB.y, hB.z, hB.w};
            #pragma unroll
            for (int p = 0; p < 4; ++p){
                const u32 hi = pack_trunc(f[2*p], f[2*p+1]);
                bhi.u[p] = hi;
                const float l0 = f[2*p]   - bitsf((hi & 0xFFFFu) << 16);
                const float l1 = f[2*p+1] - bitsf(hi & 0xFFFF0000u);
                blo.u[p] = pack_trunc(l0, l1);
            }
        }

        // acc init: own r/z tiles = gi(+bias); own n tiles = bhh_n; export tiles = 0
        const float4 u4 = *(const float4*)&uw[sq * 4];
        f32x4 acc[12];
        #pragma unroll
        for (int mt = 0; mt < 12; ++mt) acc[mt] = (f32x4){0.f, 0.f, 0.f, 0.f};
        float giN[2][4];
        #pragma unroll
        for (int mp = 0; mp < 2; ++mp){
            f32x4 gr, gz;
            #pragma unroll
            for (int r = 0; r < 4; ++r){
                const int j = 32 * g + 16 * mp + 4 * q + r;
                const float4 wr = *(const float4*)&sm.wih[j * 4];
                const float4 wz = *(const float4*)&sm.wih[(64 + j) * 4];
                const float4 wn = *(const float4*)&sm.wih[(128 + j) * 4];
                gr[r] = fmaf(wr.x,u4.x, fmaf(wr.y,u4.y, fmaf(wr.z,u4.z, fmaf(wr.w,u4.w, bR[mp][r]))));
                gz[r] = fmaf(wz.x,u4.x, fmaf(wz.y,u4.y, fmaf(wz.z,u4.z, fmaf(wz.w,u4.w, bZ[mp][r]))));
                giN[mp][r] = fmaf(wn.x,u4.x, fmaf(wn.y,u4.y, fmaf(wn.z,u4.z, fmaf(wn.w,u4.w, bNi[mp][r]))));
            }
            acc[2*g + mp]     = gr;
            acc[4 + 2*g + mp] = gz;
            acc[8 + 2*g + mp] = *(const f32x4*)&sm.lp.gnh[32*g + 16*mp + 4*q];
        }

        // MFMA partials for this K-half: 12 independent 3-deep chains
        #pragma unroll
        for (int mt = 0; mt < 12; ++mt){
            acc[mt] = __builtin_amdgcn_mfma_f32_16x16x32_bf16(ahi[mt].s, bhi.s, acc[mt], 0, 0, 0);
            acc[mt] = __builtin_amdgcn_mfma_f32_16x16x32_bf16(ahi[mt].s, blo.s, acc[mt], 0, 0, 0);
            acc[mt] = __builtin_amdgcn_mfma_f32_16x16x32_bf16(alo[mt].s, bhi.s, acc[mt], 0, 0, 0);
        }

        // export the 6 tiles OWNED BY THE OTHER WAVE into buf[t&1][1-g]
        {
            float* pg = &sm.part[t & 1][1 - g][0];
            #pragma unroll
            for (int i = 0; i < 6; ++i){
                const int mt = ((i >> 1) << 2) + 2 * (1 - g) + (i & 1);
                *(f32x4*)&pg[(i * 16 + sq) * 20 + 4 * q] = acc[mt];
            }
        }

        __syncthreads();   // single barrier per step (ping-pong makes it safe)

        // import own 6 tiles; gates; h update (own K-half rows)
        {
            const float* pi = &sm.part[t & 1][g][0];
            #pragma unroll
            for (int mp = 0; mp < 2; ++mp){
                const f32x4 ir = *(const f32x4*)&pi[((0 + mp) * 16 + sq) * 20 + 4 * q];
                const f32x4 iz = *(const f32x4*)&pi[((2 + mp) * 16 + sq) * 20 + 4 * q];
                const f32x4 in_ = *(const f32x4*)&pi[((4 + mp) * 16 + sq) * 20 + 4 * q];
                float4 hnew;
                #pragma unroll
                for (int r = 0; r < 4; ++r){
                    const float a_r = acc[2*g + mp][r]     + ir[r];
                    const float a_z = acc[4 + 2*g + mp][r] + iz[r];
                    const float ahn = acc[8 + 2*g + mp][r] + in_[r];
                    const float rr = sigmoidf_(a_r);
                    const float zz = sigmoidf_(a_z);
                    const float cand = tanhf_(fmaf(rr, ahn, giN[mp][r]));
                    const float hn = fmaf(zz, hreg[mp][r] - cand, cand);
                    hreg[mp][r] = hn;
                    ((float*)&hnew)[r] = hn;
                }
                *(float4*)&sm.h[sq * 68 + 32 * g + 16 * mp + 4 * q] = hnew;
            }
        }

        // u(t+1); prefetch x(t+2)
        uw[sq * 4 + q] = sigmoidf_(fmaf(wh0, x0, fmaf(wh1, x1, fmaf(wh2, x2, bhc))));
        const int tn = (t + 2 < 64) ? (t + 2) : 63;
        x0 = hb[tn*24 + ls]; x1 = hb[tn*24 + ls + 8]; x2 = hb[tn*24 + ls + 16];
    }
    __syncthreads();   // loop LDS dead; flip unions

    // ---- stage tail weights into the (dead) part region ----
    for (int i = tid; i < 1152; i += 128) sm.tw.wl[i]  = Wl[i];
    for (int i = tid; i <  640; i += 128) sm.tw.wcf[i] = Wcf[i];
    for (int i = tid; i <  400; i += 128) sm.tw.wcm[i] = Wcm[i];
    if (tid < 80) sm.tw.wcc[tid] = Wcc[tid];
    if (tid < 20){
        sm.tw.bcf[tid]  = bcf[tid];
        sm.tw.bcc[tid]  = bcc[tid];
        sm.tw.bcm[tid]  = bcm[tid];
        sm.tw.wfin[tid] = Wfin[tid];
    }
    if (tid < 16) sm.tw.bl[tid] = bl[tid];
    if (tid == 0) sm.tw.bfin = bfin[0];
    __syncthreads();

    // ---- tail: wave g handles b = b_base + g (wave-private LDS) ----
    {
        const int b = b_base + g;
        // Phase A
        {
            const int l = lane >> 3, o = lane & 7;
            float fv[8];
            const float vraw = feat[b * 16 + 8 + l];
            const int   bit  = ((int)feat[b * 16 + l]) & 1;
            #pragma unroll
            for (int c = 0; c < 4; ++c){
                fv[c]     = sigmoidf_(fmaf(vraw, Wv[c], bv[c]));
                fv[4 + c] = sigmoidf_(emb_phase[bit * 4 + c]);
            }
            const float* hrow = &sm.h[(g * 8 + l) * 68];
            #pragma unroll
            for (int half = 0; half < 2; ++half){
                const int oo = o + half * 8;
                float acc = sm.tw.bl[oo];
                #pragma unroll
                for (int f = 0; f < 8; ++f) acc = fmaf(fv[f], sm.tw.wl[oo * 72 + f], acc);
                for (int k = 0; k < 64; ++k) acc = fmaf(hrow[k], sm.tw.wl[oo * 72 + 8 + k], acc);
                sm.tl.line[g][l * 16 + oo] = fmaxf(acc, 0.0f);
            }
        }
        __builtin_amdgcn_wave_barrier();
        // Phase B
        {
            const int p = lane >> 3, o = lane & 7;
            const int l0 = (0x64204501u >> (p * 4)) & 15;
            const int l1 = (0x75316723u >> (p * 4)) & 15;
            sm.tl.pp[g][p * 16 + o]     = sm.tl.line[g][l0 * 16 + o]     + sm.tl.line[g][l1 * 16 + o];
            sm.tl.pp[g][p * 16 + o + 8] = sm.tl.line[g][l0 * 16 + o + 8] + sm.tl.line[g][l1 * 16 + o + 8];
        }
        __builtin_amdgcn_wave_barrier();
        // Phase C
        if (lane < 56){
            const int p  = lane / 7;
            const int qi = lane - p * 7;
            const int jl = qi + (qi >= p ? 1 : 0);
            float fmv[32];
            #pragma unroll
            for (int f = 0; f < 16; ++f){
                fmv[f]      = sm.tl.pp[g][p  * 16 + f];
                fmv[16 + f] = sm.tl.pp[g][jl * 16 + f];
            }
            const int rel = relation[p * 7 + qi] & 1;
            float ce[4];
            #pragma unroll
            for (int c = 0; c < 4; ++c) ce[c] = emb_const[rel * 4 + c];
            float m[20];
            for (int o = 0; o < 20; ++o){
                float xf = sm.tw.bcf[o];
                #pragma unroll
                for (int f = 0; f < 32; ++f) xf = fmaf(fmv[f], sm.tw.wcf[o * 32 + f], xf);
                float yc = sm.tw.bcc[o];
                #pragma unroll
                for (int c = 0; c < 4; ++c) yc = fmaf(ce[c], sm.tw.wcc[o * 4 + c], yc);
                m[o] = fmaxf(xf, 0.0f) * fmaxf(yc, 0.0f);
            }
            float fin = sm.tw.bfin;
            for (int o = 0; o < 20; ++o){
                float zz = sm.tw.bcm[o];
                #pragma unroll
                for (int c = 0; c < 20; ++c) zz = fmaf(m[c], sm.tw.wcm[o * 20 + c], zz);
                fin = fmaf(fmaxf(zz, 0.0f), sm.tw.wfin[o], fin);
            }
            sm.tl.line[g][lane] = fin;   // line dead after Phase B
        }
        __builtin_amdgcn_wave_barrier();
        if (lane < 8){
            float acc = 0.0f;
            #pragma unroll
            for (int qq = 0; qq < 7; ++qq) acc += sm.tl.line[g][lane * 7 + qq];
            out[b * 8 + lane] = acc;
        }
    }
}

extern "C" void kernel_launch(void* const* d_in, const int* in_sizes, int n_in,
                              void* d_out, int out_size, void* d_ws, size_t ws_size,
                              hipStream_t stream) {
    (void)n_in; (void)d_ws; (void)ws_size; (void)out_size;
    const float* feat      = (const float*)d_in[0];
    const float* hist      = (const float*)d_in[1];
    const int*   relation  = (const int*)d_in[2];
    const float* emb_phase = (const float*)d_in[3];
    const float* Wv        = (const float*)d_in[4];
    const float* bv        = (const float*)d_in[5];
    const float* Wh        = (const float*)d_in[6];
    const float* bh        = (const float*)d_in[7];
    const float* Wih       = (const float*)d_in[8];
    const float* Whh       = (const float*)d_in[9];
    const float* bih       = (const float*)d_in[10];
    const float* bhh       = (const float*)d_in[11];
    const float* Wl        = (const float*)d_in[12];
    const float* bl        = (const float*)d_in[13];
    const float* emb_const = (const float*)d_in[14];
    const float* Wcf       = (const float*)d_in[15];
    const float* bcf       = (const float*)d_in[16];
    const float* Wcc       = (const float*)d_in[17];
    const float* bcc       = (const float*)d_in[18];
    const float* Wcm       = (const float*)d_in[19];
    const float* bcm       = (const float*)d_in[20];
    const float* Wfin      = (const float*)d_in[21];
    const float* bfin      = (const float*)d_in[22];
    float* out = (float*)d_out;

    const int B = in_sizes[0] / 16;     // 2048
    const int nblocks = B / 2;          // 1024 blocks: 2 waves (K-halves), 2 b/block
    FRAPRQ_fused_kernel<<<nblocks, 128, 0, stream>>>(
        feat, hist, relation, emb_phase, Wv, bv, Wh, bh, Wih, Whh, bih, bhh,
        Wl, bl, emb_const, Wcf, bcf, Wcc, bcc, Wcm, bcm, Wfin, bfin, out);
}

// Round 12
// 256.961 us; speedup vs baseline: 3.5294x; 3.5294x over previous
//
#include <hip/hip_runtime.h>

typedef unsigned short u16;
typedef unsigned int   u32;

typedef __attribute__((ext_vector_type(8))) short short8;   // 8 bf16 (4 VGPRs)
typedef __attribute__((ext_vector_type(4))) float f32x4;    // MFMA acc

union Frag { u32 u[4]; short8 s; };

__device__ __forceinline__ u32 fbits(float f){ union{float f;u32 u;}x; x.f=f; return x.u; }
__device__ __forceinline__ float bitsf(u32 u){ union{u32 u;float f;}x; x.u=u; return x.f; }
__device__ __forceinline__ u32 pack_trunc(float a, float b){
    return __builtin_amdgcn_perm(fbits(b), fbits(a), 0x07060302u);
}
__device__ __forceinline__ u32 bf16_rne(float a){
    u32 u = fbits(a); return (u + 0x7FFFu + ((u >> 16) & 1u)) >> 16;
}
__device__ __forceinline__ u32 pack_rne(float a, float b){
    return bf16_rne(a) | (bf16_rne(b) << 16);
}
__device__ __forceinline__ float sigmoidf_(float x){
    return __builtin_amdgcn_rcpf(1.0f + __expf(-x));
}
__device__ __forceinline__ float tanhf_(float x){
    return 1.0f - 2.0f * __builtin_amdgcn_rcpf(__expf(2.0f * x) + 1.0f);
}

// LDS: 40,448 B. part: ping-pong [buf][dest-wave][tile*16+sq][20]; stride 20 dw
// -> bank-quad 4*((5sq+q)%8): permutation over 8 consecutive lanes, conflict-free b128.
struct __align__(16) SharedMem {
    union {
        float part[2][2][6 * 16 * 20];   // 30720 B — loop only
        struct {                         // 9476 B — tail weights
            float wl[1152];
            float bl[16];
            float wcf[640];
            float bcf[20];
            float wcc[80];
            float bcc[20];
            float wcm[400];
            float bcm[20];
            float wfin[20];
            float bfin;
        } tw;
    };
    float h[16 * 68];      // 4352 B — hidden state [sq][k]
    float wih[768];        // 3072 B
    union {
        struct { float u[2][64]; float gnh[64]; } lp;          // loop: 768 B
        struct { float line[2][128]; float pp[2][128]; } tl;   // tail: 2048 B
    };
};

__global__ __launch_bounds__(128, 2)
void FRAPRQ_fused_kernel(
    const float* __restrict__ feat,       // (B,16)
    const float* __restrict__ hist,       // (B,64,24)
    const int*   __restrict__ relation,   // (8,7)
    const float* __restrict__ emb_phase,  // (2,4)
    const float* __restrict__ Wv,         // (4,1)
    const float* __restrict__ bv,         // (4)
    const float* __restrict__ Wh,         // (4,3)
    const float* __restrict__ bh,         // (4)
    const float* __restrict__ Wih,        // (192,4)
    const float* __restrict__ Whh,        // (192,64)
    const float* __restrict__ bih,        // (192)
    const float* __restrict__ bhh,        // (192)
    const float* __restrict__ Wl,         // (16,72)
    const float* __restrict__ bl,         // (16)
    const float* __restrict__ emb_const,  // (2,4)
    const float* __restrict__ Wcf,        // (20,32)
    const float* __restrict__ bcf,        // (20)
    const float* __restrict__ Wcc,        // (20,4)
    const float* __restrict__ bcc,        // (20)
    const float* __restrict__ Wcm,        // (20,20)
    const float* __restrict__ bcm,        // (20)
    const float* __restrict__ Wfin,      // (1,20)
    const float* __restrict__ bfin,      // (1)
    float* __restrict__ out)             // (B,8)
{
    __shared__ SharedMem sm;
    const int tid  = threadIdx.x;        // 0..127
    const int g    = tid >> 6;           // K-half: 0 -> k 0..31, 1 -> k 32..63
    const int lane = tid & 63;
    const int sq   = lane & 15;          // MFMA column: local seq (2 b's x 8 lanes)
    const int q    = lane >> 4;          // MFMA quad
    const int b_base = blockIdx.x * 2;

    // ---- cooperative staging ----
    for (int i = tid; i < 768; i += 128) sm.wih[i] = Wih[i];
    if (tid < 64) sm.lp.gnh[tid] = bhh[128 + tid];
    for (int i = tid; i < 16 * 68; i += 128) sm.h[i] = 0.0f;

    // ---- A-fragments, SLOT-PERMUTED so all acc[] indices are literals ----
    // slot i<6  : OWN tiles    (gate = i>>1, mp = i&1, row-tile = 4*gate + 2*g     + mp)
    // slot 6+i  : PARTNER tiles(gate = i>>1, mp = i&1, row-tile = 4*gate + 2*(1-g) + mp)
    // g only affects the LOAD ADDRESS (memory), never a register-array index.
    Frag ahi[12], alo[12];
    #pragma unroll
    for (int i = 0; i < 12; ++i){
        const int gate = (i < 6) ? (i >> 1) : ((i - 6) >> 1);
        const int mp   = (i < 6) ? (i & 1)  : ((i - 6) & 1);
        const int own  = (i < 6) ? g : (1 - g);
        const int mt   = 4 * gate + 2 * own + mp;
        const float* wp = Whh + (16 * mt + sq) * 64 + 32 * g + 8 * q;
        float f[8];
        #pragma unroll
        for (int k = 0; k < 8; ++k) f[k] = wp[k];
        #pragma unroll
        for (int p = 0; p < 4; ++p){
            const u32 hi = pack_rne(f[2*p], f[2*p+1]);
            ahi[i].u[p] = hi;
            const float l0 = f[2*p]   - bitsf((hi & 0xFFFFu) << 16);
            const float l1 = f[2*p+1] - bitsf(hi & 0xFFFF0000u);
            alo[i].u[p] = pack_rne(l0, l1);
        }
    }

    // ---- per-lane biases for OWNED rows j = 32g + 16mp + 4q + r ----
    float bR[2][4], bZ[2][4], bNi[2][4];
    #pragma unroll
    for (int mp = 0; mp < 2; ++mp){
        #pragma unroll
        for (int r = 0; r < 4; ++r){
            const int j = 32 * g + 16 * mp + 4 * q + r;
            bR[mp][r]  = bih[j]       + bhh[j];
            bZ[mp][r]  = bih[64 + j]  + bhh[64 + j];
            bNi[mp][r] = bih[128 + j];
        }
    }

    // ---- u path: lane computes u[s=sq][c=q]; redundant per wave ----
    const int bs = b_base + (sq >> 3);
    const int ls = sq & 7;
    const float* hb = hist + (size_t)bs * 1536;
    const float wh0 = Wh[q*3+0], wh1 = Wh[q*3+1], wh2 = Wh[q*3+2], bhc = bh[q];
    float* uw = &sm.lp.u[g][0];
    {
        const float y0 = hb[ls], y1 = hb[ls + 8], y2 = hb[ls + 16];
        uw[sq * 4 + q] = sigmoidf_(fmaf(wh0, y0, fmaf(wh1, y1, fmaf(wh2, y2, bhc))));
    }
    float x0 = hb[24 + ls], x1 = hb[24 + ls + 8], x2 = hb[24 + ls + 16];

    float hreg[2][4];
    #pragma unroll
    for (int mp = 0; mp < 2; ++mp)
        #pragma unroll
        for (int r = 0; r < 4; ++r) hreg[mp][r] = 0.0f;

    __syncthreads();   // staging + h init visible

    #pragma unroll 1
    for (int t = 0; t < 64; ++t){
        // B fragment from h(t-1), own K-half (rows this wave wrote itself)
        Frag bhi, blo;
        {
            const float4 hA = *(const float4*)&sm.h[sq*68 + 32*g + 8*q];
            const float4 hB = *(const float4*)&sm.h[sq*68 + 32*g + 8*q + 4];
            const float f[8] = {hA.x, hA.y, hA.z, hA.w, hB.x, hB.y, hB.z, hB.w};
            #pragma unroll
            for (int p = 0; p < 4; ++p){
                const u32 hi = pack_trunc(f[2*p], f[2*p+1]);
                bhi.u[p] = hi;
                const float l0 = f[2*p]   - bitsf((hi & 0xFFFFu) << 16);
                const float l1 = f[2*p+1] - bitsf(hi & 0xFFFF0000u);
                blo.u[p] = pack_trunc(l0, l1);
            }
        }

        // acc init (ALL literal indices): own r = gi_r, own z = gi_z, own n = bhh_n
        const float4 u4 = *(const float4*)&uw[sq * 4];
        f32x4 acc[12];
        float giN[2][4];
        #pragma unroll
        for (int mp = 0; mp < 2; ++mp){
            f32x4 gr, gz;
            #pragma unroll
            for (int r = 0; r < 4; ++r){
                const int j = 32 * g + 16 * mp + 4 * q + r;
                const float4 wr = *(const float4*)&sm.wih[j * 4];
                const float4 wz = *(const float4*)&sm.wih[(64 + j) * 4];
                const float4 wn = *(const float4*)&sm.wih[(128 + j) * 4];
                gr[r] = fmaf(wr.x,u4.x, fmaf(wr.y,u4.y, fmaf(wr.z,u4.z, fmaf(wr.w,u4.w, bR[mp][r]))));
                gz[r] = fmaf(wz.x,u4.x, fmaf(wz.y,u4.y, fmaf(wz.z,u4.z, fmaf(wz.w,u4.w, bZ[mp][r]))));
                giN[mp][r] = fmaf(wn.x,u4.x, fmaf(wn.y,u4.y, fmaf(wn.z,u4.z, fmaf(wn.w,u4.w, bNi[mp][r]))));
            }
            acc[0 + mp] = gr;
            acc[2 + mp] = gz;
            acc[4 + mp] = *(const f32x4*)&sm.lp.gnh[32*g + 16*mp + 4*q];
        }
        #pragma unroll
        for (int i = 6; i < 12; ++i) acc[i] = (f32x4){0.f, 0.f, 0.f, 0.f};

        // MFMA partials: 12 slots, literal indices, 3-deep chains
        #pragma unroll
        for (int i = 0; i < 12; ++i){
            acc[i] = __builtin_amdgcn_mfma_f32_16x16x32_bf16(ahi[i].s, bhi.s, acc[i], 0, 0, 0);
            acc[i] = __builtin_amdgcn_mfma_f32_16x16x32_bf16(ahi[i].s, blo.s, acc[i], 0, 0, 0);
            acc[i] = __builtin_amdgcn_mfma_f32_16x16x32_bf16(alo[i].s, bhi.s, acc[i], 0, 0, 0);
        }

        // export partner's 6 tiles (slots 6..11) into buf[t&1][1-g], tile order i
        {
            float* pg = &sm.part[t & 1][1 - g][0];
            #pragma unroll
            for (int i = 0; i < 6; ++i)
                *(f32x4*)&pg[(i * 16 + sq) * 20 + 4 * q] = acc[6 + i];
        }

        __syncthreads();   // single barrier per step (ping-pong)

        // import own 6 tiles; gates; h update (own K-half rows)
        {
            const float* pi = &sm.part[t & 1][g][0];
            #pragma unroll
            for (int mp = 0; mp < 2; ++mp){
                const f32x4 ir  = *(const f32x4*)&pi[((0 + mp) * 16 + sq) * 20 + 4 * q];
                const f32x4 iz  = *(const f32x4*)&pi[((2 + mp) * 16 + sq) * 20 + 4 * q];
                const f32x4 in_ = *(const f32x4*)&pi[((4 + mp) * 16 + sq) * 20 + 4 * q];
                float4 hnew;
                #pragma unroll
                for (int r = 0; r < 4; ++r){
                    const float a_r = acc[0 + mp][r] + ir[r];
                    const float a_z = acc[2 + mp][r] + iz[r];
                    const float ahn = acc[4 + mp][r] + in_[r];
                    const float rr = sigmoidf_(a_r);
                    const float zz = sigmoidf_(a_z);
                    const float cand = tanhf_(fmaf(rr, ahn, giN[mp][r]));
                    const float hn = fmaf(zz, hreg[mp][r] - cand, cand);
                    hreg[mp][r] = hn;
                    ((float*)&hnew)[r] = hn;
                }
                *(float4*)&sm.h[sq * 68 + 32 * g + 16 * mp + 4 * q] = hnew;
            }
        }

        // u(t+1); prefetch x(t+2)
        uw[sq * 4 + q] = sigmoidf_(fmaf(wh0, x0, fmaf(wh1, x1, fmaf(wh2, x2, bhc))));
        const int tn = (t + 2 < 64) ? (t + 2) : 63;
        x0 = hb[tn*24 + ls]; x1 = hb[tn*24 + ls + 8]; x2 = hb[tn*24 + ls + 16];
    }
    __syncthreads();   // loop LDS dead; flip unions

    // ---- stage tail weights into the (dead) part region ----
    for (int i = tid; i < 1152; i += 128) sm.tw.wl[i]  = Wl[i];
    for (int i = tid; i <  640; i += 128) sm.tw.wcf[i] = Wcf[i];
    for (int i = tid; i <  400; i += 128) sm.tw.wcm[i] = Wcm[i];
    if (tid < 80) sm.tw.wcc[tid] = Wcc[tid];
    if (tid < 20){
        sm.tw.bcf[tid]  = bcf[tid];
        sm.tw.bcc[tid]  = bcc[tid];
        sm.tw.bcm[tid]  = bcm[tid];
        sm.tw.wfin[tid] = Wfin[tid];
    }
    if (tid < 16) sm.tw.bl[tid] = bl[tid];
    if (tid == 0) sm.tw.bfin = bfin[0];
    __syncthreads();

    // ---- tail: wave g handles b = b_base + g (wave-private LDS) ----
    {
        const int b = b_base + g;
        // Phase A
        {
            const int l = lane >> 3, o = lane & 7;
            float fv[8];
            const float vraw = feat[b * 16 + 8 + l];
            const int   bit  = ((int)feat[b * 16 + l]) & 1;
            #pragma unroll
            for (int c = 0; c < 4; ++c){
                fv[c]     = sigmoidf_(fmaf(vraw, Wv[c], bv[c]));
                fv[4 + c] = sigmoidf_(emb_phase[bit * 4 + c]);
            }
            const float* hrow = &sm.h[(g * 8 + l) * 68];
            #pragma unroll
            for (int half = 0; half < 2; ++half){
                const int oo = o + half * 8;
                float acc = sm.tw.bl[oo];
                #pragma unroll
                for (int f = 0; f < 8; ++f) acc = fmaf(fv[f], sm.tw.wl[oo * 72 + f], acc);
                for (int k = 0; k < 64; ++k) acc = fmaf(hrow[k], sm.tw.wl[oo * 72 + 8 + k], acc);
                sm.tl.line[g][l * 16 + oo] = fmaxf(acc, 0.0f);
            }
        }
        __builtin_amdgcn_wave_barrier();
        // Phase B
        {
            const int p = lane >> 3, o = lane & 7;
            const int l0 = (0x64204501u >> (p * 4)) & 15;
            const int l1 = (0x75316723u >> (p * 4)) & 15;
            sm.tl.pp[g][p * 16 + o]     = sm.tl.line[g][l0 * 16 + o]     + sm.tl.line[g][l1 * 16 + o];
            sm.tl.pp[g][p * 16 + o + 8] = sm.tl.line[g][l0 * 16 + o + 8] + sm.tl.line[g][l1 * 16 + o + 8];
        }
        __builtin_amdgcn_wave_barrier();
        // Phase C
        if (lane < 56){
            const int p  = lane / 7;
            const int qi = lane - p * 7;
            const int jl = qi + (qi >= p ? 1 : 0);
            float fmv[32];
            #pragma unroll
            for (int f = 0; f < 16; ++f){
                fmv[f]      = sm.tl.pp[g][p  * 16 + f];
                fmv[16 + f] = sm.tl.pp[g][jl * 16 + f];
            }
            const int rel = relation[p * 7 + qi] & 1;
            float ce[4];
            #pragma unroll
            for (int c = 0; c < 4; ++c) ce[c] = emb_const[rel * 4 + c];
            float m[20];
            for (int o = 0; o < 20; ++o){
                float xf = sm.tw.bcf[o];
                #pragma unroll
                for (int f = 0; f < 32; ++f) xf = fmaf(fmv[f], sm.tw.wcf[o * 32 + f], xf);
                float yc = sm.tw.bcc[o];
                #pragma unroll
                for (int c = 0; c < 4; ++c) yc = fmaf(ce[c], sm.tw.wcc[o * 4 + c], yc);
                m[o] = fmaxf(xf, 0.0f) * fmaxf(yc, 0.0f);
            }
            float fin = sm.tw.bfin;
            for (int o = 0; o < 20; ++o){
                float zz = sm.tw.bcm[o];
                #pragma unroll
                for (int c = 0; c < 20; ++c) zz = fmaf(m[c], sm.tw.wcm[o * 20 + c], zz);
                fin = fmaf(fmaxf(zz, 0.0f), sm.tw.wfin[o], fin);
            }
            sm.tl.line[g][lane] = fin;   // line dead after Phase B
        }
        __builtin_amdgcn_wave_barrier();
        if (lane < 8){
            float acc = 0.0f;
            #pragma unroll
            for (int qq = 0; qq < 7; ++qq) acc += sm.tl.line[g][lane * 7 + qq];
            out[b * 8 + lane] = acc;
        }
    }
}

extern "C" void kernel_launch(void* const* d_in, const int* in_sizes, int n_in,
                              void* d_out, int out_size, void* d_ws, size_t ws_size,
                              hipStream_t stream) {
    (void)n_in; (void)d_ws; (void)ws_size; (void)out_size;
    const float* feat      = (const float*)d_in[0];
    const float* hist      = (const float*)d_in[1];
    const int*   relation  = (const int*)d_in[2];
    const float* emb_phase = (const float*)d_in[3];
    const float* Wv        = (const float*)d_in[4];
    const float* bv        = (const float*)d_in[5];
    const float* Wh        = (const float*)d_in[6];
    const float* bh        = (const float*)d_in[7];
    const float* Wih       = (const float*)d_in[8];
    const float* Whh       = (const float*)d_in[9];
    const float* bih       = (const float*)d_in[10];
    const float* bhh       = (const float*)d_in[11];
    const float* Wl        = (const float*)d_in[12];
    const float* bl        = (const float*)d_in[13];
    const float* emb_const = (const float*)d_in[14];
    const float* Wcf       = (const float*)d_in[15];
    const float* bcf       = (const float*)d_in[16];
    const float* Wcc       = (const float*)d_in[17];
    const float* bcc       = (const float*)d_in[18];
    const float* Wcm       = (const float*)d_in[19];
    const float* bcm       = (const float*)d_in[20];
    const float* Wfin      = (const float*)d_in[21];
    const float* bfin      = (const float*)d_in[22];
    float* out = (float*)d_out;

    const int B = in_sizes[0] / 16;     // 2048
    const int nblocks = B / 2;          // 1024 blocks: 2 waves (K-halves), 2 b/block
    FRAPRQ_fused_kernel<<<nblocks, 128, 0, stream>>>(
        feat, hist, relation, emb_phase, Wv, bv, Wh, bh, Wih, Whh, bih, bhh,
        Wl, bl, emb_const, Wcf, bcf, Wcc, bcc, Wcm, bcm, Wfin, bfin, out);
}